// Round 19
// baseline (432.328 us; speedup 1.0000x reference)
//
#include <hip/hip_runtime.h>

// B=16, H=W=128. Compact NHWC bf16: xf1 64ch, xf2 64ch (aliased on x1),
// xcv 96ch (81 cv + 15 zero), x1 128ch, x2 64ch, x3 32ch. Out [B,2,H,W] fp32.

typedef __bf16 bf16x8 __attribute__((ext_vector_type(8)));
typedef float f32x4 __attribute__((ext_vector_type(4)));

__device__ __forceinline__ unsigned short f2bf_bits(float f) {
  unsigned int u = __float_as_uint(f);
  unsigned int r = (u + 0x7FFFu + ((u >> 16) & 1u)) >> 16;  // RNE
  return (unsigned short)r;
}

__device__ __forceinline__ void glds16(const ushort* gp, ushort* lp) {
  __builtin_amdgcn_global_load_lds((const __attribute__((address_space(1))) void*)gp,
                                   (__attribute__((address_space(3))) void*)lp, 16, 0, 0);
}

// ---------------- fused weight prepack (all 4 layers in one dispatch) --------
__global__ __launch_bounds__(256) void prep_w_all_kernel(
    const float* __restrict__ w1, const float* __restrict__ w2,
    const float* __restrict__ w3, const float* __restrict__ w4,
    uint4* __restrict__ wp1, uint4* __restrict__ wp2,
    uint4* __restrict__ wp3, uint4* __restrict__ wp4) {
  const int bx = blockIdx.x;
  const float* w; uint4* wp; int CIN, COUT, CHUNKS, NFRAG, base;
  if (bx < 90)       { w = w1; wp = wp1; CIN = 145; COUT = 128; CHUNKS = 5; NFRAG = 8; base = 0; }
  else if (bx < 126) { w = w2; wp = wp2; CIN = 128; COUT = 64;  CHUNKS = 4; NFRAG = 4; base = 90; }
  else if (bx < 135) { w = w3; wp = wp3; CIN = 64;  COUT = 32;  CHUNKS = 2; NFRAG = 2; base = 126; }
  else               { w = w4; wp = wp4; CIN = 32;  COUT = 2;   CHUNKS = 1; NFRAG = 1; base = 135; }
  int idx = (bx - base) * 256 + threadIdx.x;
  int total = CHUNKS * 9 * NFRAG * 64;
  if (idx >= total) return;
  int lane = idx & 63;
  int fi = idx >> 6;
  int nf = fi % NFRAG;
  int t = fi / NFRAG;
  int rs = t % 9;
  int c = t / 9;
  int co = nf * 16 + (lane & 15);
  int cib = c * 32 + (lane >> 4) * 8;
  union { uint4 q; ushort s[8]; } pk;
#pragma unroll
  for (int e = 0; e < 8; ++e) {
    int ci = cib + e;
    float v = (ci < CIN && co < COUT) ? w[(co * CIN + ci) * 9 + rs] : 0.f;
    pk.s[e] = f2bf_bits(v);
  }
  wp[idx] = pk.q;
}

// ---------------- pack both: NCHW fp32 (64ch) -> compact NHWC bf16 ----------
__global__ __launch_bounds__(256) void pack_both_kernel(const float* __restrict__ f1,
                                                        const float* __restrict__ f2,
                                                        ushort* __restrict__ xf1,
                                                        ushort* __restrict__ xf2) {
  __shared__ float tile[64][132];
  const int bid0 = blockIdx.x;
  const float* src = (bid0 < 2048) ? f1 : f2;
  ushort* dst = (bid0 < 2048) ? xf1 : xf2;
  const int bid = bid0 & 2047;
  const int h = bid & 127, b = bid >> 7;
  const int tid = threadIdx.x;
  for (int e = tid; e < 64 * 128; e += 256) {
    int c = e >> 7, w = e & 127;
    tile[c][w] = src[((b * 64 + c) * 128 + h) * 128 + w];
  }
  __syncthreads();
  const int px = tid >> 1, cgb = (tid & 1) * 4;
  const long base = ((long)(b * 128 + h) * 128 + px) * 64;
#pragma unroll
  for (int e = 0; e < 4; ++e) {
    int c0 = (cgb + e) * 8;
    union { uint4 q; ushort s[8]; } pk;
#pragma unroll
    for (int k = 0; k < 8; ++k) pk.s[k] = f2bf_bits(tile[c0 + k][px]);
    *reinterpret_cast<uint4*>(&dst[base + c0]) = pk.q;
  }
}

// ---------------- cost volume via MFMA (banded GEMM) ------------------------
__global__ __launch_bounds__(256)
void cost_volume_mfma_kernel(const ushort* __restrict__ xf1,
                             const ushort* __restrict__ xf2,
                             ushort* __restrict__ xcv) {
  const int bx = blockIdx.x;            // 2048
  const int idx = bx >> 3;
  const int b = 2 * (bx & 7) + (idx >> 7);
  const int h = idx & 127;
  const int tid = threadIdx.x;
  const int lane = tid & 63;
  const int g = tid >> 6;
  const int l15 = lane & 15;
  const int lg = lane >> 4;

  __shared__ __align__(16) float sC[4][2][16][33];   // per-wave band tiles
  __shared__ __align__(16) ushort sO[96][132];       // output staging (1 row)

  {
    uint4 z = make_uint4(0u, 0u, 0u, 0u);
    uint4* p = (uint4*)sO;
#pragma unroll
    for (int j = 0; j < 7; ++j) {
      int e = tid + j * 256;
      if (e < 1584) p[e] = z;
    }
  }
  __syncthreads();

  const int w0g = g * 32;
  bf16x8 afr[2][2];
  {
    const ushort* f1p = xf1 + ((long)(b * 128 + h) * 128) * 64;
#pragma unroll
    for (int wt = 0; wt < 2; ++wt)
#pragma unroll
      for (int kc = 0; kc < 2; ++kc) {
        int pix = w0g + wt * 16 + l15;
        afr[wt][kc] = *reinterpret_cast<const bf16x8*>(f1p + pix * 64 + kc * 32 + lg * 8);
      }
  }

  const float inv = 1.0f / 64.0f;
  for (int A = 0; A < 9; ++A) {
    int fr = h - 4 + A;
    if ((unsigned)fr >= 128u) continue;
    const ushort* f2p = xf2 + ((long)(b * 128 + fr) * 128) * 64;
    bf16x8 bfr[3][2];
#pragma unroll
    for (int t = 0; t < 3; ++t)
#pragma unroll
      for (int kc = 0; kc < 2; ++kc) {
        int p = w0g - 4 + t * 16 + l15;
        uint4 v = make_uint4(0u, 0u, 0u, 0u);
        if ((unsigned)p < 128u)
          v = *reinterpret_cast<const uint4*>(f2p + (long)p * 64 + kc * 32 + lg * 8);
        bfr[t][kc] = __builtin_bit_cast(bf16x8, v);
      }
#pragma unroll
    for (int wt = 0; wt < 2; ++wt)
#pragma unroll
      for (int nt = 0; nt < 2; ++nt) {
        f32x4 acc = {0.f, 0.f, 0.f, 0.f};
        acc = __builtin_amdgcn_mfma_f32_16x16x32_bf16(afr[wt][0], bfr[wt + nt][0], acc, 0, 0, 0);
        acc = __builtin_amdgcn_mfma_f32_16x16x32_bf16(afr[wt][1], bfr[wt + nt][1], acc, 0, 0, 0);
#pragma unroll
        for (int j = 0; j < 4; ++j)
          sC[g][wt][lg * 4 + j][nt * 16 + l15] = acc[j];
      }
    const int chb = (8 - A) * 9;
#pragma unroll
    for (int wt = 0; wt < 2; ++wt) {
      int px = w0g + wt * 16 + l15;
#pragma unroll
      for (int u = 0; u < 3; ++u) {
        if (u < ((lg == 3) ? 3 : 2)) {
          int tj = lg * 2 + u;
          float v = sC[g][wt][l15][l15 + 8 - tj];
          sO[chb + tj][px] = f2bf_bits(v * inv);
        }
      }
    }
  }
  __syncthreads();

  uint4* dst = reinterpret_cast<uint4*>(xcv + ((long)(b * 128 + h) * 128) * 96);
#pragma unroll
  for (int j = 0; j < 6; ++j) {
    int t8 = j * 256 + tid;
    int px = t8 / 12;
    int ch0 = (t8 - px * 12) * 8;
    union { uint4 qq; ushort ss[8]; } pk;
#pragma unroll
    for (int k = 0; k < 8; ++k) pk.ss[k] = sO[ch0 + k][px];
    dst[t8] = pk.qq;
  }
}

// ---------------- conv1/conv2: 16-wave (1024 thr), 4-row blocks --------------
// 16 waves = 4 rows x MH x CGDIV; conv1 wave tile 64px x 64co, conv2 32 x 64.
// Acts: 6-row glds16 DOUBLE buffer. Weights: 3-rs pieces, 2-buffer rotation,
// always loading under compute. 3 barriers/chunk. 4 waves/SIMD.
template <int CA, int CB, int COUT, bool RELU>
__global__ __launch_bounds__(1024, 4)
void conv_mfma16_kernel(const ushort* __restrict__ xa, const ushort* __restrict__ xb,
                        const uint4* __restrict__ wp, const float* __restrict__ bias,
                        ushort* __restrict__ out) {
  constexpr int CHUNKS = (CA + CB) / 32;
  constexpr int NFRAG = COUT / 16;                 // 8 or 4
  constexpr int CGDIV = (COUT == 128) ? 2 : 1;
  constexpr int NFW = NFRAG / CGDIV;               // 4
  constexpr int MFW = (CGDIV == 2) ? 4 : 2;
  constexpr int MH = 128 / (MFW * 16);             // 2 or 4
  constexpr int SXN = 6 * 130 * 32;                // ushorts per act buffer
  constexpr int SX_B = 2 * SXN * 2;                // 99840
  constexpr int WPQ = 3 * NFRAG * 64;              // uint4 per wt piece
  constexpr int NSEG = WPQ / 64;                   // 24 or 12
  constexpr int SO_STRIDE = COUT + 4;
  constexpr int SO_B = 512 * SO_STRIDE * 2;
  constexpr int BASE_B = SX_B + 2 * WPQ * 16;
  constexpr int ARENA_B = (SO_B > BASE_B) ? SO_B : BASE_B;

  __shared__ __align__(16) char arena[ARENA_B];
  ushort* sXa = (ushort*)arena;
  uint4* sWt = (uint4*)(arena + SX_B);             // [2][WPQ]

  const int bx = blockIdx.x;                       // 512 blocks
  const int idx = bx >> 3;
  const int b = 2 * (bx & 7) + (idx >> 5);
  const int h0 = (idx & 31) * 4;
  const int tid = threadIdx.x;
  const int lane = tid & 63;
  const int wid = tid >> 6;                        // 0..15
  const int l15 = lane & 15, lg = lane >> 4;
  const int cg = (CGDIV == 2) ? (wid >> 3) : 0;
  const int wrem = (CGDIV == 2) ? (wid & 7) : wid;
  const int row = (MH == 2) ? (wrem >> 1) : (wrem >> 2);   // 0..3
  const int mh = wrem & (MH - 1);
  const int pbase = mh * (MFW * 16);

  f32x4 acc[MFW][NFW];
#pragma unroll
  for (int mf = 0; mf < MFW; ++mf)
#pragma unroll
    for (int nf = 0; nf < NFW; ++nf) acc[mf][nf] = {0.f, 0.f, 0.f, 0.f};

  // pre-zero pads wl=0,129 (6 tr x 2 bufs) — never staged
  if (tid < 96) {
    int bi = tid / 48, rem = tid % 48;
    int tr = rem >> 3, wz = (rem >> 2) & 1, g = rem & 3;
    int wl = wz ? 129 : 0;
    *reinterpret_cast<uint4*>(&sXa[bi * SXN + ((tr * 130 + wl) * 4 + g) * 8]) =
        make_uint4(0u, 0u, 0u, 0u);
  }
  // pre-zero OOB rows (boundary blocks)
  if (h0 == 0 || h0 == 124) {
    int trz = (h0 == 0) ? 0 : 5;
    for (int e = tid; e < 1040; e += 1024) {
      int bi = e / 520, k = e % 520;
      *reinterpret_cast<uint4*>(&sXa[bi * SXN + (trz * 520 + k) * 8]) =
          make_uint4(0u, 0u, 0u, 0u);
    }
  }

  // stage act chunk c into buffer bi: 48 segments, 16 waves x 3
  auto stage_act = [&](int c, int bi) {
    const int c0 = c * 32;
    const ushort* src; int cst, coff;
    if (CB == 0 || c0 < CA) { src = xa; cst = CA; coff = c0; }
    else                    { src = xb; cst = CB; coff = c0 - CA; }
#pragma unroll
    for (int i = 0; i < 3; ++i) {
      int sidx = wid + i * 16;          // 0..47
      int tr = sidx >> 3, seg = sidx & 7;
      int gh = h0 - 1 + tr;
      if ((unsigned)gh < 128u) {
        const ushort* rowp = src + ((long)(b * 128 + gh) * 128) * cst + coff;
        int u = seg * 64 + lane;
        int wl = 1 + (u >> 2);
        int g = lane & 3;
        int sw = (wl + (wl >> 2)) & 3;
        const ushort* gp = rowp + (long)(wl - 1) * cst + (g ^ sw) * 8;
        ushort* lp = &sXa[bi * SXN + ((tr * 130 + 1) * 4 + seg * 64) * 8];
        glds16(gp, lp);
      }
    }
  };

  // stage wt piece (c, p = rs-triple) into buffer bs (linear copy)
  auto stage_wt = [&](int c, int p, int bs) {
    const ushort* src = (const ushort*)(wp + (size_t)(c * 9 + p * 3) * NFRAG * 64);
#pragma unroll
    for (int i = 0; i < 2; ++i) {
      int sidx = wid + i * 16;
      if (sidx < NSEG) {
        ushort* lp = (ushort*)(sWt + bs * WPQ + sidx * 64);
        glds16(src + (size_t)(sidx * 64 + lane) * 8, lp);
      }
    }
  };

  // compute piece p (act row r=p, shifts s=0..2) from wt buffer bs
  auto compute = [&](int p, int bs, int bi) {
    const int tr = row + p;
#pragma unroll
    for (int s = 0; s < 3; ++s) {
      bf16x8 afr[MFW];
#pragma unroll
      for (int mf = 0; mf < MFW; ++mf) {
        int wl = pbase + mf * 16 + l15 + s;
        int sw = (wl + (wl >> 2)) & 3;
        afr[mf] = *reinterpret_cast<const bf16x8*>(
            &sXa[bi * SXN + ((tr * 130 + wl) * 4 + (lg ^ sw)) * 8]);
      }
#pragma unroll
      for (int nf = 0; nf < NFW; ++nf) {
        bf16x8 bfr = __builtin_bit_cast(bf16x8,
            sWt[bs * WPQ + (s * NFRAG + cg * NFW + nf) * 64 + lane]);
#pragma unroll
        for (int mf = 0; mf < MFW; ++mf)
          acc[mf][nf] = __builtin_amdgcn_mfma_f32_16x16x32_bf16(afr[mf], bfr, acc[mf][nf], 0, 0, 0);
      }
    }
  };

  stage_act(0, 0);
  stage_wt(0, 0, 0);
  __syncthreads();  // act0 + piece(0,0) in LDS

  for (int c = 0; c < CHUNKS; ++c) {
    const int bi = c & 1;
    if (c + 1 < CHUNKS) stage_act(c + 1, bi ^ 1);   // async, lands by sync3
    stage_wt(c, 1, (3 * c + 1) & 1);
    compute(0, (3 * c) & 1, bi);
    __syncthreads();                                 // piece(c,1) ready
    stage_wt(c, 2, (3 * c + 2) & 1);
    compute(1, (3 * c + 1) & 1, bi);
    __syncthreads();                                 // piece(c,2) ready
    if (c + 1 < CHUNKS) stage_wt(c + 1, 0, (3 * c + 3) & 1);
    compute(2, (3 * c + 2) & 1, bi);
    __syncthreads();                                 // piece(c+1,0) + act(c+1) ready
  }

  // epilogue: overlay arena with sO[512 px2][SO_STRIDE]
  ushort* sO = (ushort*)arena;
#pragma unroll
  for (int nf = 0; nf < NFW; ++nf) {
    float bs = bias[cg * NFW * 16 + nf * 16 + l15];
#pragma unroll
    for (int mf = 0; mf < MFW; ++mf) {
      int px2 = row * 128 + pbase + mf * 16 + lg * 4;
#pragma unroll
      for (int j = 0; j < 4; ++j) {
        float v = acc[mf][nf][j] + bs;
        if (RELU) v = fmaxf(v, 0.f);
        sO[(px2 + j) * SO_STRIDE + cg * NFW * 16 + nf * 16 + l15] = f2bf_bits(v);
      }
    }
  }
  __syncthreads();
  constexpr int QPP = COUT / 8;
  uint4* dst = reinterpret_cast<uint4*>(out + ((long)(b * 128 + h0) * 128) * COUT);
#pragma unroll
  for (int t0 = 0; t0 < 512 * QPP / 1024; ++t0) {
    int t = t0 * 1024 + tid;
    int px2 = t / QPP;
    int ch0 = (t & (QPP - 1)) * 8;
    union { uint4 qq; ushort ss[8]; } pk;
#pragma unroll
    for (int k = 0; k < 8; ++k) pk.ss[k] = sO[px2 * SO_STRIDE + ch0 + k];
    dst[t] = pk.qq;
  }
}

// ---------------- old implicit-GEMM template (conv3, conv4) ------------------
template <int CA, int CB, int COUT, bool RELU, bool PLANAR>
__global__ __launch_bounds__(512, 2)
void conv_mfma_kernel(const ushort* __restrict__ xa, const ushort* __restrict__ xb,
                      const uint4* __restrict__ wp, const float* __restrict__ bias,
                      void* __restrict__ outv) {
  constexpr int CHUNKS = (CA + CB) / 32;
  constexpr int NFRAG = COUT / 16;
  constexpr int NFW = (NFRAG >= 2) ? NFRAG / 2 : 1;
  constexpr int MFW = (NFRAG >= 2) ? 4 : 2;
  constexpr int SXN = 4 * 130 * 32;
  constexpr int WTQ = 9 * NFRAG * 64;
  constexpr int WTA_Q = 5 * NFRAG * 64;
  constexpr int WTB_Q = 4 * NFRAG * 64;
  constexpr int WIA = (WTA_Q + 511) / 512;
  constexpr int WIB = (WTB_Q + 511) / 512;
  constexpr int SO_STRIDE = COUT + 4;
  constexpr int STAGE_B = PLANAR ? 2048 : 2 * 128 * SO_STRIDE * 2;
  constexpr int SX_B = 2 * SXN * 2;
  constexpr int BASE_B = SX_B + (WTA_Q + WTB_Q) * 16;
  constexpr int ARENA_B = STAGE_B > BASE_B ? STAGE_B : BASE_B;

  __shared__ __align__(16) char arena[ARENA_B];
  ushort* sXa = (ushort*)arena;
  ushort* sWtA = (ushort*)(arena + SX_B);
  ushort* sWtB = (ushort*)(arena + SX_B + WTA_Q * 16);

  const int bx = blockIdx.x;
  const int idx = bx >> 3;
  const int b = 2 * (bx & 7) + (idx >> 6);
  const int h0 = (idx & 63) * 2;
  const int tid = threadIdx.x;
  const int lane = tid & 63;
  const int wid = tid >> 6;
  const int l15 = lane & 15;
  const int lg = lane >> 4;
  const int cg    = (NFRAG >= 2) ? (wid >> 2) : 0;
  const int row   = (NFRAG >= 2) ? ((wid >> 1) & 1) : (wid >> 2);
  const int pbase = (NFRAG >= 2) ? ((wid & 1) * 64) : ((wid & 3) * 32);

  f32x4 acc[MFW][NFW];
#pragma unroll
  for (int mf = 0; mf < MFW; ++mf)
#pragma unroll
    for (int nf = 0; nf < NFW; ++nf) acc[mf][nf] = {0.f, 0.f, 0.f, 0.f};

  if (tid < 64) {
    int bi = tid >> 5, tr = (tid >> 3) & 3, wz = (tid >> 2) & 1, gq = tid & 3;
    int wl = wz ? 129 : 0;
    *reinterpret_cast<uint4*>(&sXa[bi * SXN + ((tr * 130 + wl) * 4 + gq) * 8]) =
        make_uint4(0u, 0u, 0u, 0u);
  }
  if (h0 == 0 || h0 == 126) {
    const int trz = (h0 == 0) ? 0 : 3;
#pragma unroll
    for (int e = 0; e < 2; ++e) {
      int u = tid + e * 512;
      int bi = u >> 9, k = u & 511;
      *reinterpret_cast<uint4*>(&sXa[bi * SXN + ((trz * 130 + 1) * 4 + k) * 8]) =
          make_uint4(0u, 0u, 0u, 0u);
    }
  }

  auto stage = [&](int c, int bi) {
    const int c0 = c * 32;
    const ushort* src;
    int cst, coff;
    if (CB == 0 || c0 < CA) { src = xa; cst = CA; coff = c0; }
    else                    { src = xb; cst = CB; coff = c0 - CA; }
    const int tr = wid >> 1;
    const int gh = h0 - 1 + tr;
    if ((unsigned)gh < 128u) {
      const ushort* rowp = src + ((long)(b * 128 + gh) * 128) * cst + coff;
#pragma unroll
      for (int t = 0; t < 4; ++t) {
        int s = (wid & 1) * 4 + t;
        int u = s * 64 + lane;
        int wl = 1 + (u >> 2);
        int gq = lane & 3;
        int sw = (wl + (wl >> 2)) & 3;
        const ushort* gp = rowp + (long)(wl - 1) * cst + (gq ^ sw) * 8;
        ushort* lp = &sXa[bi * SXN + ((tr * 130 + 1) * 4 + s * 64) * 8];
        glds16(gp, lp);
      }
    }
  };

  auto stage_wtA = [&](int c) {
    const ushort* src = (const ushort*)(wp + (size_t)c * WTQ);
#pragma unroll
    for (int i = 0; i < WIA; ++i) {
      int e = tid + i * 512;
      if ((WTA_Q % 512) == 0 || e < WTA_Q)
        glds16(src + (size_t)e * 8, sWtA + (size_t)(tid & ~63) * 8 + (size_t)(i * 512) * 8);
    }
  };
  auto stage_wtB = [&](int c) {
    const ushort* src = (const ushort*)(wp + (size_t)c * WTQ + WTA_Q);
#pragma unroll
    for (int i = 0; i < WIB; ++i) {
      int e = tid + i * 512;
      if ((WTB_Q % 512) == 0 || e < WTB_Q)
        glds16(src + (size_t)e * 8, sWtB + (size_t)(tid & ~63) * 8 + (size_t)(i * 512) * 8);
    }
  };

  auto compute = [&](int bi, int rs0, int rs1, const ushort* wbuf) {
#pragma unroll
    for (int rs = rs0; rs < rs1; ++rs) {
      const int r = rs / 3, s = rs % 3;
      const int tr = row + r;
      bf16x8 afr[MFW];
#pragma unroll
      for (int mf = 0; mf < MFW; ++mf) {
        int wl = pbase + mf * 16 + l15 + s;
        int sw = (wl + (wl >> 2)) & 3;
        afr[mf] = *reinterpret_cast<const bf16x8*>(
            &sXa[bi * SXN + ((tr * 130 + wl) * 4 + (lg ^ sw)) * 8]);
      }
      const ushort* wrow = wbuf + (size_t)((rs - rs0) * NFRAG + cg * NFW) * 64 * 8;
#pragma unroll
      for (int nf = 0; nf < NFW; ++nf) {
        bf16x8 bfr = *reinterpret_cast<const bf16x8*>(wrow + (nf * 64 + lane) * 8);
#pragma unroll
        for (int mf = 0; mf < MFW; ++mf)
          acc[mf][nf] = __builtin_amdgcn_mfma_f32_16x16x32_bf16(afr[mf], bfr, acc[mf][nf], 0, 0, 0);
      }
    }
  };

  stage(0, 0);
  stage_wtA(0);
  __syncthreads();

  for (int c = 0; c < CHUNKS; ++c) {
    const int bi = c & 1;
    stage_wtB(c);
    if (c + 1 < CHUNKS) stage(c + 1, bi ^ 1);
    compute(bi, 0, 5, sWtA);
    __syncthreads();
    if (c + 1 < CHUNKS) stage_wtA(c + 1);
    compute(bi, 5, 9, sWtB);
    __syncthreads();
  }

  if (!PLANAR) {
    ushort* sO = (ushort*)arena;
#pragma unroll
    for (int nf = 0; nf < NFW; ++nf) {
      float bs = bias[cg * NFW * 16 + nf * 16 + l15];
#pragma unroll
      for (int mf = 0; mf < MFW; ++mf) {
        int px2 = row * 128 + pbase + mf * 16 + lg * 4;
#pragma unroll
        for (int j = 0; j < 4; ++j) {
          float v = acc[mf][nf][j] + bs;
          if (RELU) v = fmaxf(v, 0.f);
          sO[(px2 + j) * SO_STRIDE + cg * NFW * 16 + nf * 16 + l15] = f2bf_bits(v);
        }
      }
    }
    __syncthreads();
    constexpr int QPP = COUT / 8;
    uint4* dst = reinterpret_cast<uint4*>((ushort*)outv + ((long)(b * 128 + h0) * 128) * COUT);
#pragma unroll
    for (int t0 = 0; t0 < 2 * 128 * QPP / 512; ++t0) {
      int t = t0 * 512 + tid;
      int px2 = t / QPP;
      int ch0 = (t & (QPP - 1)) * 8;
      union { uint4 qq; ushort ss[8]; } pk;
#pragma unroll
      for (int k = 0; k < 8; ++k) pk.ss[k] = sO[px2 * SO_STRIDE + ch0 + k];
      dst[t] = pk.qq;
    }
  } else {
    float* sF = (float*)arena;
    if (l15 < 2) {
#pragma unroll
      for (int mf = 0; mf < MFW; ++mf) {
        int pxb = pbase + mf * 16 + lg * 4;
#pragma unroll
        for (int j = 0; j < 4; ++j)
          sF[(l15 * 2 + row) * 128 + pxb + j] = acc[mf][0][j] + bias[l15];
      }
    }
    __syncthreads();
    float* out = (float*)outv;
    if (tid < 128) {
      int ch = tid >> 6, r = (tid >> 5) & 1, qx = tid & 31;
      *reinterpret_cast<float4*>(&out[((long)(b * 2 + ch) * 128 + h0 + r) * 128 + qx * 4]) =
          *reinterpret_cast<float4*>(&sF[(ch * 2 + r) * 128 + qx * 4]);
    }
  }
}

extern "C" void kernel_launch(void* const* d_in, const int* in_sizes, int n_in,
                              void* d_out, int out_size, void* d_ws, size_t ws_size,
                              hipStream_t stream) {
  (void)in_sizes; (void)n_in; (void)out_size; (void)ws_size;
  const float* f1 = (const float*)d_in[0];
  const float* f2 = (const float*)d_in[1];
  const float* w1 = (const float*)d_in[2];
  const float* b1 = (const float*)d_in[3];
  const float* w2 = (const float*)d_in[4];
  const float* b2 = (const float*)d_in[5];
  const float* w3 = (const float*)d_in[6];
  const float* b3 = (const float*)d_in[7];
  const float* w4 = (const float*)d_in[8];
  const float* b4 = (const float*)d_in[9];

  char* ws = (char*)d_ws;
  size_t off = 0;
  ushort* xf1 = (ushort*)(ws + off); off += (size_t)262144 * 64 * 2;
  ushort* xcv = (ushort*)(ws + off); off += (size_t)262144 * 96 * 2;
  ushort* x1  = (ushort*)(ws + off); off += (size_t)262144 * 128 * 2;
  ushort* x2  = (ushort*)(ws + off); off += (size_t)262144 * 64 * 2;
  uint4* wp1 = (uint4*)(ws + off); off += (size_t)5 * 9 * 8 * 64 * 16;
  uint4* wp2 = (uint4*)(ws + off); off += (size_t)4 * 9 * 4 * 64 * 16;
  uint4* wp3 = (uint4*)(ws + off); off += (size_t)2 * 9 * 2 * 64 * 16;
  uint4* wp4 = (uint4*)(ws + off); off += (size_t)1 * 9 * 1 * 64 * 16;
  ushort* x3  = xf1;  // alias: xf1 consumed by conv1 before conv3 writes
  ushort* xf2 = x1;   // alias: xf2 dead before conv1 writes x1

  prep_w_all_kernel<<<138, 256, 0, stream>>>(w1, w2, w3, w4, wp1, wp2, wp3, wp4);
  pack_both_kernel<<<4096, 256, 0, stream>>>(f1, f2, xf1, xf2);
  cost_volume_mfma_kernel<<<2048, 256, 0, stream>>>(xf1, xf2, xcv);

  conv_mfma16_kernel<64, 96, 128, true><<<512, 1024, 0, stream>>>(xf1, xcv, wp1, b1, x1);
  conv_mfma16_kernel<128, 0, 64, true><<<512, 1024, 0, stream>>>(x1, x1, wp2, b2, x2);
  conv_mfma_kernel<64, 0, 32, true, false><<<1024, 512, 0, stream>>>(x2, x2, wp3, b3, x3);
  conv_mfma_kernel<32, 0, 16, false, true><<<1024, 512, 0, stream>>>(x3, x3, wp4, b4, d_out);
}

// Round 20
// 288.274 us; speedup vs baseline: 1.4997x; 1.4997x over previous
//
#include <hip/hip_runtime.h>

// B=16, H=W=128. Compact NHWC bf16: xf1 64ch, xf2 64ch (aliased on x1),
// xcv 96ch (81 cv + 15 zero), x1 128ch, x2 64ch, x3 32ch. Out [B,2,H,W] fp32.

typedef __bf16 bf16x8 __attribute__((ext_vector_type(8)));
typedef float f32x4 __attribute__((ext_vector_type(4)));

__device__ __forceinline__ unsigned short f2bf_bits(float f) {
  unsigned int u = __float_as_uint(f);
  unsigned int r = (u + 0x7FFFu + ((u >> 16) & 1u)) >> 16;  // RNE
  return (unsigned short)r;
}

__device__ __forceinline__ void glds16(const ushort* gp, ushort* lp) {
  __builtin_amdgcn_global_load_lds((const __attribute__((address_space(1))) void*)gp,
                                   (__attribute__((address_space(3))) void*)lp, 16, 0, 0);
}

// ---------------- fused weight prepack (all 4 layers in one dispatch) --------
__global__ __launch_bounds__(256) void prep_w_all_kernel(
    const float* __restrict__ w1, const float* __restrict__ w2,
    const float* __restrict__ w3, const float* __restrict__ w4,
    uint4* __restrict__ wp1, uint4* __restrict__ wp2,
    uint4* __restrict__ wp3, uint4* __restrict__ wp4) {
  const int bx = blockIdx.x;
  const float* w; uint4* wp; int CIN, COUT, CHUNKS, NFRAG, base;
  if (bx < 90)       { w = w1; wp = wp1; CIN = 145; COUT = 128; CHUNKS = 5; NFRAG = 8; base = 0; }
  else if (bx < 126) { w = w2; wp = wp2; CIN = 128; COUT = 64;  CHUNKS = 4; NFRAG = 4; base = 90; }
  else if (bx < 135) { w = w3; wp = wp3; CIN = 64;  COUT = 32;  CHUNKS = 2; NFRAG = 2; base = 126; }
  else               { w = w4; wp = wp4; CIN = 32;  COUT = 2;   CHUNKS = 1; NFRAG = 1; base = 135; }
  int idx = (bx - base) * 256 + threadIdx.x;
  int total = CHUNKS * 9 * NFRAG * 64;
  if (idx >= total) return;
  int lane = idx & 63;
  int fi = idx >> 6;
  int nf = fi % NFRAG;
  int t = fi / NFRAG;
  int rs = t % 9;
  int c = t / 9;
  int co = nf * 16 + (lane & 15);
  int cib = c * 32 + (lane >> 4) * 8;
  union { uint4 q; ushort s[8]; } pk;
#pragma unroll
  for (int e = 0; e < 8; ++e) {
    int ci = cib + e;
    float v = (ci < CIN && co < COUT) ? w[(co * CIN + ci) * 9 + rs] : 0.f;
    pk.s[e] = f2bf_bits(v);
  }
  wp[idx] = pk.q;
}

// ---------------- pack both: NCHW fp32 (64ch) -> compact NHWC bf16 ----------
__global__ __launch_bounds__(256) void pack_both_kernel(const float* __restrict__ f1,
                                                        const float* __restrict__ f2,
                                                        ushort* __restrict__ xf1,
                                                        ushort* __restrict__ xf2) {
  __shared__ float tile[64][132];
  const int bid0 = blockIdx.x;
  const float* src = (bid0 < 2048) ? f1 : f2;
  ushort* dst = (bid0 < 2048) ? xf1 : xf2;
  const int bid = bid0 & 2047;
  const int h = bid & 127, b = bid >> 7;
  const int tid = threadIdx.x;
  for (int e = tid; e < 64 * 128; e += 256) {
    int c = e >> 7, w = e & 127;
    tile[c][w] = src[((b * 64 + c) * 128 + h) * 128 + w];
  }
  __syncthreads();
  const int px = tid >> 1, cgb = (tid & 1) * 4;
  const long base = ((long)(b * 128 + h) * 128 + px) * 64;
#pragma unroll
  for (int e = 0; e < 4; ++e) {
    int c0 = (cgb + e) * 8;
    union { uint4 q; ushort s[8]; } pk;
#pragma unroll
    for (int k = 0; k < 8; ++k) pk.s[k] = f2bf_bits(tile[c0 + k][px]);
    *reinterpret_cast<uint4*>(&dst[base + c0]) = pk.q;
  }
}

// ---------------- cost volume via MFMA (banded GEMM) ------------------------
__global__ __launch_bounds__(256)
void cost_volume_mfma_kernel(const ushort* __restrict__ xf1,
                             const ushort* __restrict__ xf2,
                             ushort* __restrict__ xcv) {
  const int bx = blockIdx.x;            // 2048
  const int idx = bx >> 3;
  const int b = 2 * (bx & 7) + (idx >> 7);
  const int h = idx & 127;
  const int tid = threadIdx.x;
  const int lane = tid & 63;
  const int g = tid >> 6;
  const int l15 = lane & 15;
  const int lg = lane >> 4;

  __shared__ __align__(16) float sC[4][2][16][33];   // per-wave band tiles
  __shared__ __align__(16) ushort sO[96][132];       // output staging (1 row)

  {  // pre-zero sO: covers OOB f2-rows and pad channels 81..95
    uint4 z = make_uint4(0u, 0u, 0u, 0u);
    uint4* p = (uint4*)sO;
#pragma unroll
    for (int j = 0; j < 7; ++j) {
      int e = tid + j * 256;
      if (e < 1584) p[e] = z;
    }
  }
  __syncthreads();

  const int w0g = g * 32;
  bf16x8 afr[2][2];
  {
    const ushort* f1p = xf1 + ((long)(b * 128 + h) * 128) * 64;
#pragma unroll
    for (int wt = 0; wt < 2; ++wt)
#pragma unroll
      for (int kc = 0; kc < 2; ++kc) {
        int pix = w0g + wt * 16 + l15;
        afr[wt][kc] = *reinterpret_cast<const bf16x8*>(f1p + pix * 64 + kc * 32 + lg * 8);
      }
  }

  const float inv = 1.0f / 64.0f;
  for (int A = 0; A < 9; ++A) {       // f2 row = h-4+A ; tap row ii = 8-A
    int fr = h - 4 + A;
    if ((unsigned)fr >= 128u) continue;
    const ushort* f2p = xf2 + ((long)(b * 128 + fr) * 128) * 64;
    bf16x8 bfr[3][2];
#pragma unroll
    for (int t = 0; t < 3; ++t)
#pragma unroll
      for (int kc = 0; kc < 2; ++kc) {
        int p = w0g - 4 + t * 16 + l15;
        uint4 v = make_uint4(0u, 0u, 0u, 0u);
        if ((unsigned)p < 128u)
          v = *reinterpret_cast<const uint4*>(f2p + (long)p * 64 + kc * 32 + lg * 8);
        bfr[t][kc] = __builtin_bit_cast(bf16x8, v);
      }
#pragma unroll
    for (int wt = 0; wt < 2; ++wt)
#pragma unroll
      for (int nt = 0; nt < 2; ++nt) {
        f32x4 acc = {0.f, 0.f, 0.f, 0.f};
        acc = __builtin_amdgcn_mfma_f32_16x16x32_bf16(afr[wt][0], bfr[wt + nt][0], acc, 0, 0, 0);
        acc = __builtin_amdgcn_mfma_f32_16x16x32_bf16(afr[wt][1], bfr[wt + nt][1], acc, 0, 0, 0);
#pragma unroll
        for (int j = 0; j < 4; ++j)
          sC[g][wt][lg * 4 + j][nt * 16 + l15] = acc[j];
      }
    const int chb = (8 - A) * 9;
#pragma unroll
    for (int wt = 0; wt < 2; ++wt) {
      int px = w0g + wt * 16 + l15;
#pragma unroll
      for (int u = 0; u < 3; ++u) {
        if (u < ((lg == 3) ? 3 : 2)) {
          int tj = lg * 2 + u;
          float v = sC[g][wt][l15][l15 + 8 - tj];
          sO[chb + tj][px] = f2bf_bits(v * inv);
        }
      }
    }
  }
  __syncthreads();

  uint4* dst = reinterpret_cast<uint4*>(xcv + ((long)(b * 128 + h) * 128) * 96);
#pragma unroll
  for (int j = 0; j < 6; ++j) {
    int t8 = j * 256 + tid;
    int px = t8 / 12;
    int ch0 = (t8 - px * 12) * 8;
    union { uint4 qq; ushort ss[8]; } pk;
#pragma unroll
    for (int k = 0; k < 8; ++k) pk.ss[k] = sO[ch0 + k][px];
    dst[t8] = pk.qq;
  }
}

// ---------------- implicit-GEMM 3x3 conv via bf16 MFMA ----------------------
// 512 thr = 8 waves. NFRAG>=2: wave = (co-half cg, px-seg) -> 64 px x COUT/2.
// NFRAG==1 (conv4): wave = 1 row x 32 px x 16 co.
// Acts: glds16 dbuf. Weights: rs-split LDS dbuf (wtA rs0-4, wtB rs5-8).
// Counted-vmcnt barriers (round-14 structure, best measured).
template <int CA, int CB, int COUT, bool RELU, bool PLANAR>
__global__ __launch_bounds__(512, 2)
void conv_mfma_kernel(const ushort* __restrict__ xa, const ushort* __restrict__ xb,
                      const uint4* __restrict__ wp, const float* __restrict__ bias,
                      void* __restrict__ outv) {
  constexpr int CHUNKS = (CA + CB) / 32;
  constexpr int NFRAG = COUT / 16;
  constexpr int NFW = (NFRAG >= 2) ? NFRAG / 2 : 1;
  constexpr int MFW = (NFRAG >= 2) ? 4 : 2;
  constexpr int SXN = 4 * 130 * 32;
  constexpr int WTQ = 9 * NFRAG * 64;            // uint4 per weight chunk
  constexpr int WTA_Q = 5 * NFRAG * 64;          // rs 0..4
  constexpr int WTB_Q = 4 * NFRAG * 64;          // rs 5..8
  constexpr int WIA = (WTA_Q + 511) / 512;
  constexpr int WIB = (WTB_Q + 511) / 512;
  constexpr int SO_STRIDE = COUT + 4;
  constexpr int STAGE_B = PLANAR ? 2048 : 2 * 128 * SO_STRIDE * 2;
  constexpr int SX_B = 2 * SXN * 2;
  constexpr int BASE_B = SX_B + (WTA_Q + WTB_Q) * 16;
  constexpr int ARENA_B = STAGE_B > BASE_B ? STAGE_B : BASE_B;

  __shared__ __align__(16) char arena[ARENA_B];
  ushort* sXa = (ushort*)arena;
  ushort* sWtA = (ushort*)(arena + SX_B);
  ushort* sWtB = (ushort*)(arena + SX_B + WTA_Q * 16);

  const int bx = blockIdx.x;              // 1024 blocks
  const int idx = bx >> 3;
  const int b = 2 * (bx & 7) + (idx >> 6);
  const int h0 = (idx & 63) * 2;
  const int tid = threadIdx.x;
  const int lane = tid & 63;
  const int wid = tid >> 6;
  const int l15 = lane & 15;
  const int lg = lane >> 4;
  const int cg    = (NFRAG >= 2) ? (wid >> 2) : 0;
  const int row   = (NFRAG >= 2) ? ((wid >> 1) & 1) : (wid >> 2);
  const int pbase = (NFRAG >= 2) ? ((wid & 1) * 64) : ((wid & 3) * 32);
  const bool act_wave = ((unsigned)(h0 - 1 + (wid >> 1)) < 128u);  // wave-uniform

  f32x4 acc[MFW][NFW];
#pragma unroll
  for (int mf = 0; mf < MFW; ++mf)
#pragma unroll
    for (int nf = 0; nf < NFW; ++nf) acc[mf][nf] = {0.f, 0.f, 0.f, 0.f};

  if (tid < 64) {
    int bi = tid >> 5, tr = (tid >> 3) & 3, wz = (tid >> 2) & 1, gq = tid & 3;
    int wl = wz ? 129 : 0;
    *reinterpret_cast<uint4*>(&sXa[bi * SXN + ((tr * 130 + wl) * 4 + gq) * 8]) =
        make_uint4(0u, 0u, 0u, 0u);
  }
  if (h0 == 0 || h0 == 126) {
    const int trz = (h0 == 0) ? 0 : 3;
#pragma unroll
    for (int e = 0; e < 2; ++e) {
      int u = tid + e * 512;
      int bi = u >> 9, k = u & 511;
      *reinterpret_cast<uint4*>(&sXa[bi * SXN + ((trz * 130 + 1) * 4 + k) * 8]) =
          make_uint4(0u, 0u, 0u, 0u);
    }
  }

  auto stage = [&](int c, int bi) {
    const int c0 = c * 32;
    const ushort* src;
    int cst, coff;
    if (CB == 0 || c0 < CA) { src = xa; cst = CA; coff = c0; }
    else                    { src = xb; cst = CB; coff = c0 - CA; }
    const int tr = wid >> 1;
    const int gh = h0 - 1 + tr;
    if ((unsigned)gh < 128u) {
      const ushort* rowp = src + ((long)(b * 128 + gh) * 128) * cst + coff;
#pragma unroll
      for (int t = 0; t < 4; ++t) {
        int s = (wid & 1) * 4 + t;
        int u = s * 64 + lane;
        int wl = 1 + (u >> 2);
        int gq = lane & 3;
        int sw = (wl + (wl >> 2)) & 3;
        const ushort* gp = rowp + (long)(wl - 1) * cst + (gq ^ sw) * 8;
        ushort* lp = &sXa[bi * SXN + ((tr * 130 + 1) * 4 + s * 64) * 8];
        glds16(gp, lp);
      }
    }
  };

  auto stage_wtA = [&](int c) {
    const ushort* src = (const ushort*)(wp + (size_t)c * WTQ);
#pragma unroll
    for (int i = 0; i < WIA; ++i) {
      int e = tid + i * 512;
      if ((WTA_Q % 512) == 0 || e < WTA_Q)
        glds16(src + (size_t)e * 8, sWtA + (size_t)(tid & ~63) * 8 + (size_t)(i * 512) * 8);
    }
  };
  auto stage_wtB = [&](int c) {
    const ushort* src = (const ushort*)(wp + (size_t)c * WTQ + WTA_Q);
#pragma unroll
    for (int i = 0; i < WIB; ++i) {
      int e = tid + i * 512;
      if ((WTB_Q % 512) == 0 || e < WTB_Q)
        glds16(src + (size_t)e * 8, sWtB + (size_t)(tid & ~63) * 8 + (size_t)(i * 512) * 8);
    }
  };

  auto compute = [&](int bi, int rs0, int rs1, const ushort* wbuf) {
#pragma unroll
    for (int rs = rs0; rs < rs1; ++rs) {
      const int r = rs / 3, s = rs % 3;
      const int tr = row + r;
      bf16x8 afr[MFW];
#pragma unroll
      for (int mf = 0; mf < MFW; ++mf) {
        int wl = pbase + mf * 16 + l15 + s;
        int sw = (wl + (wl >> 2)) & 3;
        afr[mf] = *reinterpret_cast<const bf16x8*>(
            &sXa[bi * SXN + ((tr * 130 + wl) * 4 + (lg ^ sw)) * 8]);
      }
      const ushort* wrow = wbuf + (size_t)((rs - rs0) * NFRAG + cg * NFW) * 64 * 8;
#pragma unroll
      for (int nf = 0; nf < NFW; ++nf) {
        bf16x8 bfr = *reinterpret_cast<const bf16x8*>(wrow + (nf * 64 + lane) * 8);
#pragma unroll
        for (int mf = 0; mf < MFW; ++mf)
          acc[mf][nf] = __builtin_amdgcn_mfma_f32_16x16x32_bf16(afr[mf], bfr, acc[mf][nf], 0, 0, 0);
      }
    }
  };

  stage(0, 0);
  stage_wtA(0);
  __syncthreads();  // act0 + wtA(0) in LDS

  for (int c = 0; c < CHUNKS; ++c) {
    const int bi = c & 1;
    stage_wtB(c);                                    // oldest in flight
    const bool act_issued = (c + 1 < CHUNKS) && act_wave;
    if (c + 1 < CHUNKS) stage(c + 1, bi ^ 1);        // 4 newer loads (if act_wave)
    compute(bi, 0, 5, sWtA);
    // barrier1: need wtB(c) only; keep act(c+1)'s 4 loads in flight
    if (act_issued) asm volatile("s_waitcnt vmcnt(4)" ::: "memory");
    else            asm volatile("s_waitcnt vmcnt(0)" ::: "memory");
    __builtin_amdgcn_s_barrier();
    asm volatile("" ::: "memory");
    if (c + 1 < CHUNKS) stage_wtA(c + 1);
    compute(bi, 5, 9, sWtB);
    // barrier2: drain everything (act(c+1) + wtA(c+1) needed next chunk)
    asm volatile("s_waitcnt vmcnt(0)" ::: "memory");
    __builtin_amdgcn_s_barrier();
    asm volatile("" ::: "memory");
  }

  if (!PLANAR) {
    ushort* sO = (ushort*)arena;
#pragma unroll
    for (int nf = 0; nf < NFW; ++nf) {
      float bs = bias[cg * NFW * 16 + nf * 16 + l15];
#pragma unroll
      for (int mf = 0; mf < MFW; ++mf) {
        int px2 = row * 128 + pbase + mf * 16 + lg * 4;
#pragma unroll
        for (int j = 0; j < 4; ++j) {
          float v = acc[mf][nf][j] + bs;
          if (RELU) v = fmaxf(v, 0.f);
          sO[(px2 + j) * SO_STRIDE + cg * NFW * 16 + nf * 16 + l15] = f2bf_bits(v);
        }
      }
    }
    __syncthreads();
    constexpr int QPP = COUT / 8;
    uint4* dst = reinterpret_cast<uint4*>((ushort*)outv + ((long)(b * 128 + h0) * 128) * COUT);
#pragma unroll
    for (int t0 = 0; t0 < 2 * 128 * QPP / 512; ++t0) {
      int t = t0 * 512 + tid;
      int px2 = t / QPP;
      int ch0 = (t & (QPP - 1)) * 8;
      union { uint4 qq; ushort ss[8]; } pk;
#pragma unroll
      for (int k = 0; k < 8; ++k) pk.ss[k] = sO[px2 * SO_STRIDE + ch0 + k];
      dst[t] = pk.qq;
    }
  } else {
    float* sF = (float*)arena;
    if (l15 < 2) {
#pragma unroll
      for (int mf = 0; mf < MFW; ++mf) {
        int pxb = pbase + mf * 16 + lg * 4;
#pragma unroll
        for (int j = 0; j < 4; ++j)
          sF[(l15 * 2 + row) * 128 + pxb + j] = acc[mf][0][j] + bias[l15];
      }
    }
    __syncthreads();
    float* out = (float*)outv;
    if (tid < 128) {
      int ch = tid >> 6, r = (tid >> 5) & 1, qx = tid & 31;
      *reinterpret_cast<float4*>(&out[((long)(b * 2 + ch) * 128 + h0 + r) * 128 + qx * 4]) =
          *reinterpret_cast<float4*>(&sF[(ch * 2 + r) * 128 + qx * 4]);
    }
  }
}

extern "C" void kernel_launch(void* const* d_in, const int* in_sizes, int n_in,
                              void* d_out, int out_size, void* d_ws, size_t ws_size,
                              hipStream_t stream) {
  (void)in_sizes; (void)n_in; (void)out_size; (void)ws_size;
  const float* f1 = (const float*)d_in[0];
  const float* f2 = (const float*)d_in[1];
  const float* w1 = (const float*)d_in[2];
  const float* b1 = (const float*)d_in[3];
  const float* w2 = (const float*)d_in[4];
  const float* b2 = (const float*)d_in[5];
  const float* w3 = (const float*)d_in[6];
  const float* b3 = (const float*)d_in[7];
  const float* w4 = (const float*)d_in[8];
  const float* b4 = (const float*)d_in[9];

  char* ws = (char*)d_ws;
  size_t off = 0;
  ushort* xf1 = (ushort*)(ws + off); off += (size_t)262144 * 64 * 2;
  ushort* xcv = (ushort*)(ws + off); off += (size_t)262144 * 96 * 2;
  ushort* x1  = (ushort*)(ws + off); off += (size_t)262144 * 128 * 2;
  ushort* x2  = (ushort*)(ws + off); off += (size_t)262144 * 64 * 2;
  uint4* wp1 = (uint4*)(ws + off); off += (size_t)5 * 9 * 8 * 64 * 16;
  uint4* wp2 = (uint4*)(ws + off); off += (size_t)4 * 9 * 4 * 64 * 16;
  uint4* wp3 = (uint4*)(ws + off); off += (size_t)2 * 9 * 2 * 64 * 16;
  uint4* wp4 = (uint4*)(ws + off); off += (size_t)1 * 9 * 1 * 64 * 16;
  ushort* x3  = xf1;  // alias: xf1 consumed by conv1 before conv3 writes
  ushort* xf2 = x1;   // alias: xf2 dead before conv1 writes x1

  prep_w_all_kernel<<<138, 256, 0, stream>>>(w1, w2, w3, w4, wp1, wp2, wp3, wp4);
  pack_both_kernel<<<4096, 256, 0, stream>>>(f1, f2, xf1, xf2);
  cost_volume_mfma_kernel<<<2048, 256, 0, stream>>>(xf1, xf2, xcv);

  conv_mfma_kernel<64, 96, 128, true, false><<<1024, 512, 0, stream>>>(xf1, xcv, wp1, b1, x1);
  conv_mfma_kernel<128, 0, 64, true, false><<<1024, 512, 0, stream>>>(x1, x1, wp2, b2, x2);
  conv_mfma_kernel<64, 0, 32, true, false><<<1024, 512, 0, stream>>>(x2, x2, wp3, b3, x3);
  conv_mfma_kernel<32, 0, 16, false, true><<<1024, 512, 0, stream>>>(x3, x3, wp4, b4, d_out);
}